// Round 11
// baseline (372.797 us; speedup 1.0000x reference)
//
#include <hip/hip_runtime.h>

#define DIM   256
#define HW_   1024
#define NROWS 32768
#define KEMB  4096

// ---------------- ws layout ----------------
// [0,       131072)  int    idx[32768]
// [131072,  262144)  float  S[32768]
// [262144,  278528)  float  E[4096]
// [278528,  278536)  double loss_sum
// [278536,  278540)  int    done
// [278592,  409664)  int    cnt[32768]
// [540736,  3686464) int    cand[32768][24]
// [3686464, 5783616) short  ebuf[1048576]  (bf16, 16x16-frag-major, 2 MB)
#define WS_S_OFF    131072
#define WS_E_OFF    262144
#define WS_LOSS_OFF 278528
#define WS_DONE_OFF 278536
#define WS_CNT_OFF  278592
#define WS_CAND_OFF 540736
#define WS_EBUF_OFF 3686464
#define WS_NEEDED   5783616
#define RESCUE_W    1.5e-4f
#define CAND_CAP    24

typedef __attribute__((ext_vector_type(8))) short bf16x8;
typedef __attribute__((ext_vector_type(4))) float f32x4;

__device__ __forceinline__ unsigned short f2bf(float v) {
  unsigned u = __float_as_uint(v);
  return (unsigned short)((u + 0x7FFFu + ((u >> 16) & 1u)) >> 16);
}
// monotone float<->unsigned (atomicMin on possibly-negative g) [R6-proven]
__device__ __forceinline__ unsigned encf(float f) {
  unsigned u = __float_as_uint(f);
  return ((int)u < 0) ? ~u : (u | 0x80000000u);
}
__device__ __forceinline__ float decf(unsigned k) {
  unsigned u = (k & 0x80000000u) ? (k ^ 0x80000000u) : ~k;
  return __uint_as_float(u);
}

// ---------- numpy-pairwise row sums of squares ----------
__device__ __forceinline__ float np_sumsq_128(const float* q, int stride) {
#pragma clang fp contract(off)
  float r[8];
#pragma unroll
  for (int i = 0; i < 8; ++i) { float v = q[i * stride]; r[i] = v * v; }
  for (int blk = 8; blk < 128; blk += 8) {
#pragma unroll
    for (int i = 0; i < 8; ++i) {
      float v = q[(blk + i) * stride];
      float sq = v * v;
      r[i] = r[i] + sq;
    }
  }
  return ((r[0] + r[1]) + (r[2] + r[3])) + ((r[4] + r[5]) + (r[6] + r[7]));
}

// ---------- prep: norms+init [0,144) + 16x16-frag pack [144,656) ----------
__global__ __launch_bounds__(256) void prep_kernel(
    const float* __restrict__ z, const float* __restrict__ emb,
    float* __restrict__ S, float* __restrict__ E, short* __restrict__ ebuf,
    double* __restrict__ loss_sum, int* __restrict__ done, int do_filter) {
#pragma clang fp contract(off)
  if (blockIdx.x < 144) {
    int t = blockIdx.x * 256 + threadIdx.x;
    if (t == 0) { loss_sum[0] = 0.0; done[0] = 0; }
    if (t < NROWS) {
      int b = t >> 10, hw = t & 1023;
      const float* p = z + (size_t)b * (DIM * HW_) + hw;
      float s0 = np_sumsq_128(p, HW_);
      float s1 = np_sumsq_128(p + 128 * HW_, HW_);
      S[t] = s0 + s1;
    } else if (t < NROWS + KEMB) {
      int j = t - NROWS;
      const float* p = emb + (size_t)j * DIM;
      float s0 = np_sumsq_128(p, 1);
      float s1 = np_sumsq_128(p + 128, 1);
      E[j] = s0 + s1;
    }
  } else {
    if (!do_filter) return;
    int u = (blockIdx.x - 144) * 256 + threadIdx.x;   // 0..131071
    int lane = u & 63;
    int ks = (u >> 6) & 7;
    int g16 = u >> 9;
    int j = g16 * 16 + (lane & 15);
    int kb = ks * 32 + (lane >> 4) * 8;
    const float* p = emb + (size_t)j * DIM + kb;
    short out[8];
#pragma unroll
    for (int i = 0; i < 8; ++i) out[i] = (short)f2bf(p[i]);
    *(bf16x8*)(ebuf + (size_t)u * 8) = *(bf16x8*)out;
  }
}

// ---------- filter v3: SINGLE-sweep 16x16x32 MFMA + running threshold ----------
// 512 blocks x 4 waves; block = 64 rows, wave w = j-quarter. MFMA body is
// byte-identical to the R5/R10-proven filter2 sweep. Per group: fold group
// row-min into LDS atomicMin (encf), read thr = running_min + W, emit (j,g).
// Correctness: thr_stale >= min_full + W >= g(true winner) always -> winner
// emitted; extras pruned by final-thr compaction at writeout; cap overflow
// -> exact full-scan fallback in rescue. Groups 0,1 skip emission (thr=inf)
// and are replayed at the end with the final thr.
__global__ __launch_bounds__(256, 2) void filter3_kernel(
    const float* __restrict__ z, const short* __restrict__ ebuf,
    const float* __restrict__ E, int* __restrict__ cnt_g,
    int* __restrict__ cand_g) {
  __shared__ unsigned rowmin_e[64];
  __shared__ int   cnt_l[64];
  __shared__ int   cand_l[64][CAND_CAP];
  __shared__ float gval_l[64][CAND_CAP];

  const int t = threadIdx.x;
  const int w = t >> 6, lane = t & 63;
  const int quad = lane >> 4, l16 = lane & 15;
  const int nb = blockIdx.x * 64;
  const int b = nb >> 10, hwb = nb & 1023;   // 64 | 1024: no b straddle

  if (t < 64) { rowmin_e[t] = 0xFFFFFFFFu; cnt_l[t] = 0; }

  // ---- one-time A load + bf16 convert (64 rows, mt=4) [R5-proven] ----
  bf16x8 a[4][8];
  const float* zb = z + (size_t)b * (DIM * HW_) + hwb + l16;
#pragma unroll
  for (int mt = 0; mt < 4; ++mt) {
    const float* zp = zb + mt * 16;
#pragma unroll
    for (int ks = 0; ks < 8; ++ks) {
      short tmp[8];
#pragma unroll
      for (int i = 0; i < 8; ++i)
        tmp[i] = (short)f2bf(zp[(size_t)(ks * 32 + quad * 8 + i) * HW_]);
      a[mt][ks] = *(bf16x8*)tmp;
    }
  }
  __syncthreads();

  const f32x4 zero = {0.0f, 0.0f, 0.0f, 0.0f};

  auto do_group = [&](int grp, bool fold, bool emit) {
    const int jb = w * 1024 + grp * 32;
    const int g16b = jb >> 4;
    f32x4 acc[2][4];
#pragma unroll
    for (int jt = 0; jt < 2; ++jt)
#pragma unroll
      for (int mt = 0; mt < 4; ++mt) acc[jt][mt] = zero;
#pragma unroll
    for (int ks = 0; ks < 8; ++ks) {
      bf16x8 bfr[2];
#pragma unroll
      for (int jt = 0; jt < 2; ++jt)
        bfr[jt] = *(const bf16x8*)(ebuf +
            ((size_t)(g16b + jt) * 8 + ks) * 512 + lane * 8);
#pragma unroll
      for (int jt = 0; jt < 2; ++jt)
#pragma unroll
        for (int mt = 0; mt < 4; ++mt)
          acc[jt][mt] = __builtin_amdgcn_mfma_f32_16x16x32_bf16(
              a[mt][ks], bfr[jt], acc[jt][mt], 0, 0, 0);
    }
    float Ej0 = E[jb + l16];
    float Ej1 = E[jb + 16 + l16];
#pragma unroll
    for (int mt = 0; mt < 4; ++mt)
#pragma unroll
      for (int rg = 0; rg < 4; ++rg) {
        const int rl = mt * 16 + quad * 4 + rg;
        float g0 = fmaf(-2.0f, acc[0][mt][rg], Ej0);
        float g1 = fmaf(-2.0f, acc[1][mt][rg], Ej1);
        if (fold) {
          float m = fminf(g0, g1);
#pragma unroll
          for (int mask = 1; mask <= 8; mask <<= 1)
            m = fminf(m, __shfl_xor(m, mask, 64));
          if (l16 == 0) atomicMin(&rowmin_e[rl], encf(m));
        }
        if (emit) {
          float thr = decf(rowmin_e[rl]) + RESCUE_W;
          if (g0 <= thr) {
            int slot = atomicAdd(&cnt_l[rl], 1);
            if (slot < CAND_CAP) {
              cand_l[rl][slot] = jb + l16;
              gval_l[rl][slot] = g0;
            }
          }
          if (g1 <= thr) {
            int slot = atomicAdd(&cnt_l[rl], 1);
            if (slot < CAND_CAP) {
              cand_l[rl][slot] = jb + 16 + l16;
              gval_l[rl][slot] = g1;
            }
          }
        }
      }
  };

  for (int grp = 0; grp < 32; ++grp) do_group(grp, true, grp >= 2);
  // replay the two primed groups for emission with the (near-)final thr
  do_group(0, false, true);
  do_group(1, false, true);

  __syncthreads();
  if (t < 64) {
    int c = cnt_l[t];
    if (c > CAND_CAP) {
      cnt_g[nb + t] = KEMB;               // signal: exact full-scan fallback
    } else {
      float thrF = decf(rowmin_e[t]) + RESCUE_W;
      int o = 0;
      for (int p = 0; p < c; ++p)
        if (gval_l[t][p] <= thrF)
          cand_g[(size_t)(nb + t) * CAND_CAP + o++] = cand_l[t][p];
      cnt_g[nb + t] = o;
    }
  }
}

// ---------- rescue: exact np-order chains over per-row candidates ----------
__global__ __launch_bounds__(256) void exact_cand_kernel(
    const float* __restrict__ z, const float* __restrict__ emb,
    const float* __restrict__ S, const float* __restrict__ E,
    const int* __restrict__ cnt_g, const int* __restrict__ cand_g,
    int* __restrict__ idx_out, float* __restrict__ idxf_out) {
  int row = blockIdx.x * 256 + threadIdx.x;
  int b = row >> 10, hw = row & 1023;
  const float* zr = z + (size_t)b * (DIM * HW_) + hw;   // z[k] at zr[k*1024]
  const float s = S[row];
  int c = cnt_g[row];
  float bd = 3.0e38f; int bj = 0x7fffffff;
  if (c <= CAND_CAP) {
    for (int p = 0; p < c; ++p) {
      int j = cand_g[(size_t)row * CAND_CAP + p];
      const float* e = emb + (size_t)j * DIM;
      float acc = 0.0f;
#pragma unroll 8
      for (int k4 = 0; k4 < 64; ++k4) {          // sequential k ascending
        float4 ev = *(const float4*)(e + k4 * 4);
        acc = fmaf(zr[(size_t)(k4 * 4 + 0) * HW_], ev.x, acc);
        acc = fmaf(zr[(size_t)(k4 * 4 + 1) * HW_], ev.y, acc);
        acc = fmaf(zr[(size_t)(k4 * 4 + 2) * HW_], ev.z, acc);
        acc = fmaf(zr[(size_t)(k4 * 4 + 3) * HW_], ev.w, acc);
      }
      float d = fmaf(-2.0f, acc, s + E[j]);
      if (d < bd || (d == bd && j < bj)) { bd = d; bj = j; }
    }
  } else {
    for (int j = 0; j < KEMB; ++j) {             // overflow fallback (exact)
      const float* e = emb + (size_t)j * DIM;
      float acc = 0.0f;
      for (int k4 = 0; k4 < 64; ++k4) {
        float4 ev = *(const float4*)(e + k4 * 4);
        acc = fmaf(zr[(size_t)(k4 * 4 + 0) * HW_], ev.x, acc);
        acc = fmaf(zr[(size_t)(k4 * 4 + 1) * HW_], ev.y, acc);
        acc = fmaf(zr[(size_t)(k4 * 4 + 2) * HW_], ev.z, acc);
        acc = fmaf(zr[(size_t)(k4 * 4 + 3) * HW_], ev.w, acc);
      }
      float d = fmaf(-2.0f, acc, s + E[j]);
      if (d < bd || (d == bd && j < bj)) { bd = d; bj = j; }
    }
  }
  idx_out[row] = bj;
  idxf_out[row] = (float)bj;
}

// ---------- fallback fp32 kernel (R2 version, known-passing) ----------
#define RT 64
#define JT 256
#define KC 16
__global__ __launch_bounds__(256, 2) void dist_argmin_kernel(
    const float* __restrict__ z, const float* __restrict__ emb,
    const float* __restrict__ S, const float* __restrict__ E,
    int* __restrict__ idx_out, float* __restrict__ idxf_out) {
  __shared__ float zt[DIM * RT];
  __shared__ float et[KC * JT];
  const int t  = threadIdx.x;
  const int g  = t & 31;
  const int tr = t >> 5;
  const int nb = blockIdx.x * RT;
  const int b  = nb >> 10;
  const int hwb = nb & 1023;
  const float* zb = z + (size_t)b * (DIM * HW_) + hwb;
#pragma unroll
  for (int i = 0; i < 16; ++i) {
    int flat = t + i * 256;
    int k  = flat >> 4;
    int r4 = flat & 15;
    float4 v = *(const float4*)(zb + (size_t)k * HW_ + r4 * 4);
    *(float4*)(zt + flat * 4) = v;
  }
  float bestd[8];
  int   bestj[8];
#pragma unroll
  for (int i = 0; i < 8; ++i) { bestd[i] = 3.0e38f; bestj[i] = 0; }
  float Sreg[8];
#pragma unroll
  for (int rr = 0; rr < 8; ++rr) Sreg[rr] = S[nb + tr * 8 + rr];
  float4 pf[4];
#pragma unroll
  for (int q = 0; q < 4; ++q) {
    int cid = q * 256 + t;
    pf[q] = *(const float4*)(emb + (size_t)(cid >> 2) * DIM + (cid & 3) * 4);
  }
  for (int jt = 0; jt < KEMB / JT; ++jt) {
    float acc[8][8];
#pragma unroll
    for (int rr = 0; rr < 8; ++rr)
#pragma unroll
      for (int c = 0; c < 8; ++c) acc[rr][c] = 0.0f;
    for (int kc = 0; kc < DIM / KC; ++kc) {
      __syncthreads();
#pragma unroll
      for (int q = 0; q < 4; ++q) {
        int cid = q * 256 + t;
        int j = cid >> 2, k4 = cid & 3;
        et[(k4 * 4 + 0) * JT + j] = pf[q].x;
        et[(k4 * 4 + 1) * JT + j] = pf[q].y;
        et[(k4 * 4 + 2) * JT + j] = pf[q].z;
        et[(k4 * 4 + 3) * JT + j] = pf[q].w;
      }
      int s = jt * (DIM / KC) + kc + 1;
      if (s < (KEMB / JT) * (DIM / KC)) {
        int njt = s >> 4, nkc = s & 15;
        const float* base = emb + (size_t)njt * JT * DIM + nkc * KC;
#pragma unroll
        for (int q = 0; q < 4; ++q) {
          int cid = q * 256 + t;
          pf[q] = *(const float4*)(base + (size_t)(cid >> 2) * DIM + (cid & 3) * 4);
        }
      }
      __syncthreads();
      const float* ztk = zt + (kc * KC) * RT;
#pragma unroll
      for (int kk = 0; kk < KC; ++kk) {
        float4 z0 = *(const float4*)(ztk + kk * RT + tr * 8);
        float4 z1 = *(const float4*)(ztk + kk * RT + tr * 8 + 4);
        float2 e0 = *(const float2*)(et + kk * JT + g * 2);
        float2 e1 = *(const float2*)(et + kk * JT + 64 + g * 2);
        float2 e2 = *(const float2*)(et + kk * JT + 128 + g * 2);
        float2 e3 = *(const float2*)(et + kk * JT + 192 + g * 2);
        float zr[8] = {z0.x, z0.y, z0.z, z0.w, z1.x, z1.y, z1.z, z1.w};
        float ev[8] = {e0.x, e0.y, e1.x, e1.y, e2.x, e2.y, e3.x, e3.y};
#pragma unroll
        for (int rr = 0; rr < 8; ++rr)
#pragma unroll
          for (int c = 0; c < 8; ++c)
            acc[rr][c] = fmaf(zr[rr], ev[c], acc[rr][c]);
      }
    }
    int jb = jt * JT;
    float Ereg[8];
#pragma unroll
    for (int c = 0; c < 8; ++c)
      Ereg[c] = E[jb + (c >> 1) * 64 + g * 2 + (c & 1)];
#pragma unroll
    for (int rr = 0; rr < 8; ++rr)
#pragma unroll
      for (int c = 0; c < 8; ++c) {
        float A = Sreg[rr] + Ereg[c];
        float d = fmaf(-2.0f, acc[rr][c], A);
        int j = jb + (c >> 1) * 64 + g * 2 + (c & 1);
        if (d < bestd[rr] || (d == bestd[rr] && j < bestj[rr])) {
          bestd[rr] = d; bestj[rr] = j;
        }
      }
  }
  __syncthreads();
  float* rd = et;
  int*   rj = (int*)(et + 2048);
#pragma unroll
  for (int rr = 0; rr < 8; ++rr) {
    rd[(tr * 8 + rr) * 32 + g] = bestd[rr];
    rj[(tr * 8 + rr) * 32 + g] = bestj[rr];
  }
  __syncthreads();
  if (t < RT) {
    float bd = rd[t * 32];
    int   bj = rj[t * 32];
    for (int c = 1; c < 32; ++c) {
      float d2 = rd[t * 32 + c];
      int   j2 = rj[t * 32 + c];
      if (d2 < bd || (d2 == bd && j2 < bj)) { bd = d2; bj = j2; }
    }
    idx_out[nb + t]  = bj;
    idxf_out[nb + t] = (float)bj;
  }
}

// ---------- epilogue v2 (R9-proven): LDS-staged gather + STE + loss ----------
#define EPAD 257
__global__ __launch_bounds__(256) void epilogue_kernel(
    const float* __restrict__ z, const float* __restrict__ emb,
    const int* __restrict__ idx, float* __restrict__ out0,
    double* __restrict__ loss_sum, int* __restrict__ done,
    float* __restrict__ out_loss) {
#pragma clang fp contract(off)
  __shared__ float eq[64 * EPAD];
  __shared__ int   iv_l[64];
  __shared__ double wsum[4];
  const int t = threadIdx.x, w = t >> 6, lane = t & 63;
  const int nb = blockIdx.x * 64;
  const int b = nb >> 10, hwb = nb & 1023;

  if (t < 64) iv_l[t] = idx[nb + t];
  __syncthreads();
  const float4* emb4 = (const float4*)emb;
#pragma unroll
  for (int i = 0; i < 16; ++i) {
    int r = w * 16 + i;
    float4 v = emb4[(size_t)iv_l[r] * 64 + lane];
    *(float4*)(eq + r * EPAD + lane * 4) = v;
  }
  __syncthreads();

  double acc = 0.0;
  const float* zb = z + (size_t)b * (DIM * HW_) + hwb;
  float* ob = out0 + (size_t)b * (DIM * HW_) + hwb;
  for (int dc = 0; dc < 64; ++dc) {
    int d = dc * 4 + w;
    float zp = zb[(size_t)d * HW_ + lane];
    float zq = eq[lane * EPAD + d];
    float td = zq - zp;                   // fl(z_q - zp)
    ob[(size_t)d * HW_ + lane] = zp + td; // fl(zp + fl(z_q - zp))
    acc += (double)(td * td);
  }
#pragma unroll
  for (int off = 32; off > 0; off >>= 1) acc += __shfl_down(acc, off, 64);
  if (lane == 0) wsum[w] = acc;
  __syncthreads();
  if (t == 0) {
    double bsum = (wsum[0] + wsum[1]) + (wsum[2] + wsum[3]);
    atomicAdd(loss_sum, bsum);
    __threadfence();
    int prev = atomicAdd(done, 1);
    if (prev == 511) {
      double m = loss_sum[0] / 8388608.0;
      float mf = (float)m;
      float bb = 10.0f * mf;
      out_loss[0] = mf + bb;
    }
  }
}

extern "C" void kernel_launch(void* const* d_in, const int* in_sizes, int n_in,
                              void* d_out, int out_size, void* d_ws, size_t ws_size,
                              hipStream_t stream) {
  const float* z   = (const float*)d_in[0];
  const float* emb = (const float*)d_in[1];
  float* out = (float*)d_out;
  char* ws = (char*)d_ws;
  int*      idx  = (int*)ws;
  float*    S    = (float*)(ws + WS_S_OFF);
  float*    E    = (float*)(ws + WS_E_OFF);
  double*   ls   = (double*)(ws + WS_LOSS_OFF);
  int*      done = (int*)(ws + WS_DONE_OFF);
  int*      cnt  = (int*)(ws + WS_CNT_OFF);
  int*      cand = (int*)(ws + WS_CAND_OFF);
  short*    ebuf = (short*)(ws + WS_EBUF_OFF);

  const int do_filter = (ws_size >= (size_t)WS_NEEDED) ? 1 : 0;

  prep_kernel<<<656, 256, 0, stream>>>(z, emb, S, E, ebuf, ls, done, do_filter);

  if (do_filter) {
    filter3_kernel<<<512, 256, 0, stream>>>(z, ebuf, E, cnt, cand);
    exact_cand_kernel<<<128, 256, 0, stream>>>(z, emb, S, E, cnt, cand, idx,
                                               out + 8388609);
  } else {
    dist_argmin_kernel<<<NROWS / RT, 256, 0, stream>>>(z, emb, S, E, idx,
                                                       out + 8388609);
  }

  epilogue_kernel<<<512, 256, 0, stream>>>(z, emb, idx, out, ls, done,
                                           out + 8388608);
}